// Round 1
// baseline (216.773 us; speedup 1.0000x reference)
//
#include <hip/hip_runtime.h>
#include <stdint.h>

#define N_ROWS 100000
#define EPS 1e-6f

typedef float f32x4 __attribute__((ext_vector_type(4)));
typedef __bf16 bf16x8 __attribute__((ext_vector_type(8)));

__device__ __forceinline__ ushort f2bf(float f) {
  union { float f; uint32_t u; } v; v.f = f;
  uint32_t u = v.u;
  return (ushort)((u + 0x7FFFu + ((u >> 16) & 1u)) >> 16);
}

// ---- W f32 -> bf16 pre-convert (512x512 = 262144 elems) ----
__global__ __launch_bounds__(256) void wconv_kernel(const float* __restrict__ W,
                                                    ushort* __restrict__ Wbf) {
  int i = (blockIdx.x * 256 + threadIdx.x) * 4;
  float4 v = *(const float4*)(W + i);
  ushort4 o;
  o.x = f2bf(v.x); o.y = f2bf(v.y); o.z = f2bf(v.z); o.w = f2bf(v.w);
  *(ushort4*)(Wbf + i) = o;
}

// ---- fused gather + GEMM(bf16 MFMA) + bias + relu + layernorm ----
// block: 512 threads = 8 waves; output tile 64 rows x 512 cols.
// wave w owns cols [w*64, w*64+64): acc[4][4] fragments of 16x16x32.
__global__ __launch_bounds__(512) void fused_kernel(
    const float* __restrict__ f1, const float* __restrict__ f2,
    const float* __restrict__ f3, const float* __restrict__ f4,
    const int* __restrict__ i1, const int* __restrict__ i2,
    const int* __restrict__ i3, const int* __restrict__ i4,
    const ushort* __restrict__ Wbf, const float* __restrict__ bias,
    const float* __restrict__ gamma, const float* __restrict__ beta,
    float* __restrict__ out) {
  // LDS: B tile [512 rows(j)][32 k] bf16, chunk-swizzled; A tile [64][32] bf16.
  __shared__ ushort Bl[512 * 32];  // 32 KB
  __shared__ ushort Al[64 * 32];   // 4 KB

  const int t = threadIdx.x;
  const int w = t >> 6;        // wave 0..7
  const int l = t & 63;
  const int cl = l & 15;
  const int gq = l >> 4;       // k-chunk group 0..3
  const int blk = blockIdx.x;

  // ---- A staging setup: thread t covers row t>>3, k-elems (t&7)*4 .. +4
  const int arow = t >> 3;
  const int e8 = t & 7;
  int gi = blk * 64 + arow;
  int gic = gi < N_ROWS ? gi : (N_ROWS - 1);
  const float* ap0 = f1 + (size_t)i1[gic] * 128 + e8 * 4;
  const float* ap1 = f2 + (size_t)i2[gic] * 128 + e8 * 4;
  const float* ap2 = f3 + (size_t)i3[gic] * 128 + e8 * 4;
  const float* ap3 = f4 + (size_t)i4[gic] * 128 + e8 * 4;
  // swizzled ds_write offset (ushort units): chunk XOR'd by (row>>1)&3
  const int achunk = (e8 >> 1) ^ ((arow >> 1) & 3);
  const int awoff = arow * 32 + achunk * 8 + (e8 & 1) * 4;

  // ---- B staging setup: per issue q (0..3): j = q*128 + (t>>2), chunk c = t&3.
  // LDS dest is linear (global_load_lds); global source address pre-swizzled.
  const int jb = w * 16 + (l >> 2);             // j within 128-group
  const int csw = (l & 3) ^ ((jb >> 1) & 3);    // swizzled source chunk
  const ushort* bsrc0 = Wbf + jb * 512 + csw * 8;

  // ---- fragment read offset (ushort units), same for A and B tiles:
  // row cl (within 16-block), element-chunk gq, swizzle XOR (cl>>1)&3
  const int roff = cl * 32 + ((gq ^ ((cl >> 1) & 3)) * 8);

  f32x4 acc[4][4];
#pragma unroll
  for (int rb = 0; rb < 4; ++rb)
#pragma unroll
    for (int cb = 0; cb < 4; ++cb)
      acc[rb][cb] = (f32x4){0.f, 0.f, 0.f, 0.f};

#pragma unroll
  for (int tbl = 0; tbl < 4; ++tbl) {
    const float* ap = (tbl == 0) ? ap0 : (tbl == 1) ? ap1 : (tbl == 2) ? ap2 : ap3;
#pragma unroll
    for (int kq = 0; kq < 4; ++kq) {
      const int kt = tbl * 4 + kq;
      __syncthreads();  // previous iteration's LDS reads complete
      // A stage: gather f32x4, convert, swizzled ds_write (8B)
      float4 av = *(const float4*)(ap + kq * 32);
      ushort4 ab;
      ab.x = f2bf(av.x); ab.y = f2bf(av.y); ab.z = f2bf(av.z); ab.w = f2bf(av.w);
      *(ushort4*)(Al + awoff) = ab;
      // B stage: 4x global_load_lds (16B/lane), linear LDS, swizzled source
#pragma unroll
      for (int q = 0; q < 4; ++q) {
        const ushort* g = bsrc0 + q * 65536 + kt * 32;
        void* lb = (void*)((char*)Bl + q * 8192 + w * 1024);  // wave-uniform
        __builtin_amdgcn_global_load_lds(
            (const __attribute__((address_space(1))) void*)g,
            (__attribute__((address_space(3))) void*)lb, 16, 0, 0);
      }
      __syncthreads();  // waits vmcnt(0) lgkmcnt(0)
      // fragments + 16 MFMA
      bf16x8 af[4], bfr[4];
#pragma unroll
      for (int rb = 0; rb < 4; ++rb)
        af[rb] = *(const bf16x8*)(Al + rb * 512 + roff);
#pragma unroll
      for (int cb = 0; cb < 4; ++cb)
        bfr[cb] = *(const bf16x8*)(Bl + w * 2048 + cb * 512 + roff);
#pragma unroll
      for (int rb = 0; rb < 4; ++rb)
#pragma unroll
        for (int cb = 0; cb < 4; ++cb)
          acc[rb][cb] = __builtin_amdgcn_mfma_f32_16x16x32_bf16(
              af[rb], bfr[cb], acc[rb][cb], 0, 0, 0);
    }
  }

  // ---- epilogue: bias + relu + layernorm(512) fused ----
  const int wcol = w * 64;
  float bia[4], gam[4], bet[4];
#pragma unroll
  for (int cb = 0; cb < 4; ++cb) {
    int col = wcol + cb * 16 + cl;
    bia[cb] = bias[col];
    gam[cb] = gamma[col];
    bet[cb] = beta[col];
  }

  __syncthreads();  // all waves done with Bl; reuse as reduction buffer
  float2* red = (float2*)Bl;  // [64 rows][8 waves]

#pragma unroll
  for (int rb = 0; rb < 4; ++rb) {
#pragma unroll
    for (int r = 0; r < 4; ++r) {
      float s = 0.f, ss = 0.f;
#pragma unroll
      for (int cb = 0; cb < 4; ++cb) {
        float v = acc[rb][cb][r] + bia[cb];
        v = fmaxf(v, 0.f);
        acc[rb][cb][r] = v;
        s += v;
        ss += v * v;
      }
      // reduce over the 16 lanes holding this row's 64 cols of this wave
#pragma unroll
      for (int m = 1; m < 16; m <<= 1) {
        s += __shfl_xor(s, m);
        ss += __shfl_xor(ss, m);
      }
      if (cl == 0) {
        int row = rb * 16 + gq * 4 + r;
        red[row * 8 + w] = make_float2(s, ss);
      }
    }
  }
  __syncthreads();

#pragma unroll
  for (int rb = 0; rb < 4; ++rb) {
#pragma unroll
    for (int r = 0; r < 4; ++r) {
      int row = rb * 16 + gq * 4 + r;
      float S = 0.f, SS = 0.f;
#pragma unroll
      for (int wv = 0; wv < 8; ++wv) {
        float2 p = red[row * 8 + wv];
        S += p.x;
        SS += p.y;
      }
      float mu = S * (1.f / 512.f);
      float var = SS * (1.f / 512.f) - mu * mu;
      float rstd = rsqrtf(var + EPS);
      int g = blk * 64 + row;
      if (g < N_ROWS) {
        float* orow = out + (size_t)g * 512 + wcol;
#pragma unroll
        for (int cb = 0; cb < 4; ++cb)
          orow[cb * 16 + cl] = (acc[rb][cb][r] - mu) * rstd * gam[cb] + bet[cb];
      }
    }
  }
}

extern "C" void kernel_launch(void* const* d_in, const int* in_sizes, int n_in,
                              void* d_out, int out_size, void* d_ws, size_t ws_size,
                              hipStream_t stream) {
  const float* f1 = (const float*)d_in[0];
  const int* i1 = (const int*)d_in[1];
  const float* f2 = (const float*)d_in[2];
  const int* i2 = (const int*)d_in[3];
  const float* f3 = (const float*)d_in[4];
  const int* i3 = (const int*)d_in[5];
  const float* f4 = (const float*)d_in[6];
  const int* i4 = (const int*)d_in[7];
  const float* W = (const float*)d_in[8];
  const float* b = (const float*)d_in[9];
  const float* gm = (const float*)d_in[10];
  const float* bt = (const float*)d_in[11];
  float* out = (float*)d_out;
  ushort* Wbf = (ushort*)d_ws;  // 512 KB bf16 W

  wconv_kernel<<<256, 256, 0, stream>>>(W, Wbf);
  fused_kernel<<<(N_ROWS + 63) / 64, 512, 0, stream>>>(
      f1, f2, f3, f4, i1, i2, i3, i4, Wbf, b, gm, bt, out);
}

// Round 2
// 159.724 us; speedup vs baseline: 1.3572x; 1.3572x over previous
//
#include <hip/hip_runtime.h>
#include <stdint.h>

#define N_ROWS 100000
#define EPS 1e-6f

typedef float f32x4 __attribute__((ext_vector_type(4)));
typedef __bf16 bf16x8 __attribute__((ext_vector_type(8)));

__device__ __forceinline__ ushort f2bf(float f) {
  union { float f; uint32_t u; } v; v.f = f;
  uint32_t u = v.u;
  return (ushort)((u + 0x7FFFu + ((u >> 16) & 1u)) >> 16);
}

// ---- W f32 -> bf16 fragment-linear rearrange ----
// Wf layout: offset = ((j16*16 + kt)*64 + lane)*8 bf16, where
// lane=(cl,gq): holds W[j16*16+cl][kt*32+gq*8 .. +8].
// A wave's fragment load = 64 lanes x 16B contiguous = 1KB coalesced.
__global__ __launch_bounds__(256) void wconv2_kernel(const float* __restrict__ W,
                                                     ushort* __restrict__ Wf) {
  int t = blockIdx.x * 256 + threadIdx.x;  // 0..32767
  int frag = t >> 6;                       // 0..511
  int lane = t & 63;
  int j = (frag >> 4) * 16 + (lane & 15);
  int kb = (frag & 15) * 32 + (lane >> 4) * 8;
  const float* src = W + j * 512 + kb;
  float4 a = *(const float4*)src;
  float4 b = *(const float4*)(src + 4);
  ushort4 lo, hi;
  lo.x = f2bf(a.x); lo.y = f2bf(a.y); lo.z = f2bf(a.z); lo.w = f2bf(a.w);
  hi.x = f2bf(b.x); hi.y = f2bf(b.y); hi.z = f2bf(b.z); hi.w = f2bf(b.w);
  ushort* dst = Wf + (size_t)t * 8;
  *(ushort4*)dst = lo;
  *(ushort4*)(dst + 4) = hi;
}

// ---- fused gather + GEMM(bf16 MFMA) + bias + relu + layernorm ----
// 512 threads = 8 waves; tile 64 rows x 512 cols; wave w -> cols [64w,64w+64).
// B: direct global->VGPR from fragment-linear Wf (L2-resident, no LDS/barrier).
// A: LDS double-buffered, 1-step prefetch, 1 barrier per K-step.
__global__ __launch_bounds__(512, 4) void fused2_kernel(
    const float* __restrict__ f1, const float* __restrict__ f2,
    const float* __restrict__ f3, const float* __restrict__ f4,
    const int* __restrict__ i1, const int* __restrict__ i2,
    const int* __restrict__ i3, const int* __restrict__ i4,
    const ushort* __restrict__ Wf, const float* __restrict__ bias,
    const float* __restrict__ gamma, const float* __restrict__ beta,
    float* __restrict__ out) {
  __shared__ ushort Al[2][64 * 32];  // 8 KB A double-buffer
  __shared__ float2 red[64 * 8];     // 4 KB LN cross-wave reduce

  const int t = threadIdx.x;
  const int w = t >> 6;   // wave 0..7
  const int l = t & 63;
  const int cl = l & 15;
  const int gq = l >> 4;
  const int blk = blockIdx.x;

  // A staging: thread t covers row t>>3, k-elems (t&7)*4 .. +4 (within 32-k tile)
  const int arow = t >> 3;
  const int e8 = t & 7;
  int gi = blk * 64 + arow;
  int gic = gi < N_ROWS ? gi : (N_ROWS - 1);
  const float* ap0 = f1 + (size_t)i1[gic] * 128 + e8 * 4;
  const float* ap1 = f2 + (size_t)i2[gic] * 128 + e8 * 4;
  const float* ap2 = f3 + (size_t)i3[gic] * 128 + e8 * 4;
  const float* ap3 = f4 + (size_t)i4[gic] * 128 + e8 * 4;
  // swizzled ds_write offset (ushort units)
  const int achunk = (e8 >> 1) ^ ((arow >> 1) & 3);
  const int awoff = arow * 32 + achunk * 8 + (e8 & 1) * 4;
  // swizzled fragment read offset (ushort units)
  const int roff = cl * 32 + ((gq ^ ((cl >> 1) & 3)) * 8);

  // B fragment base: wave w, fragment (cb,kt) at Bbase + cb*8192 + kt*512
  const ushort* Bbase = Wf + (size_t)w * 4 * 8192 + (size_t)l * 8;

  f32x4 acc[4][4];
#pragma unroll
  for (int rb = 0; rb < 4; ++rb)
#pragma unroll
    for (int cb = 0; cb < 4; ++cb)
      acc[rb][cb] = (f32x4){0.f, 0.f, 0.f, 0.f};

  // prologue: stage k-tile 0 into buf 0
  {
    float4 av = *(const float4*)ap0;
    ushort4 ab;
    ab.x = f2bf(av.x); ab.y = f2bf(av.y); ab.z = f2bf(av.z); ab.w = f2bf(av.w);
    *(ushort4*)(Al[0] + awoff) = ab;
  }
  __syncthreads();

#pragma unroll
  for (int kt = 0; kt < 16; ++kt) {
    const int cur = kt & 1;
    // prefetch A for step kt+1 (issue early; consumed after MFMAs)
    float4 av;
    if (kt < 15) {
      const int t2 = (kt + 1) >> 2;  // compile-time (loop unrolled)
      const int k2 = (kt + 1) & 3;
      const float* ap = (t2 == 0) ? ap0 : (t2 == 1) ? ap1 : (t2 == 2) ? ap2 : ap3;
      av = *(const float4*)(ap + k2 * 32);
    }
    // B fragments for this step: 4 x 1KB coalesced loads from L2
    bf16x8 bfr[4];
#pragma unroll
    for (int cb = 0; cb < 4; ++cb)
      bfr[cb] = *(const bf16x8*)(Bbase + cb * 8192 + kt * 512);
    // A fragments from LDS
    bf16x8 af[4];
#pragma unroll
    for (int rb = 0; rb < 4; ++rb)
      af[rb] = *(const bf16x8*)(Al[cur] + rb * 512 + roff);
    // 16 MFMA
#pragma unroll
    for (int cb = 0; cb < 4; ++cb)
#pragma unroll
      for (int rb = 0; rb < 4; ++rb)
        acc[rb][cb] = __builtin_amdgcn_mfma_f32_16x16x32_bf16(
            af[rb], bfr[cb], acc[rb][cb], 0, 0, 0);
    // write prefetched A into the other buffer
    if (kt < 15) {
      ushort4 ab;
      ab.x = f2bf(av.x); ab.y = f2bf(av.y); ab.z = f2bf(av.z); ab.w = f2bf(av.w);
      *(ushort4*)(Al[cur ^ 1] + awoff) = ab;
    }
    __syncthreads();
  }

  // ---- epilogue: bias + relu + layernorm(512) ----
  const int wcol = w * 64;
  float bia[4], gam[4], bet[4];
#pragma unroll
  for (int cb = 0; cb < 4; ++cb) {
    int col = wcol + cb * 16 + cl;
    bia[cb] = bias[col];
    gam[cb] = gamma[col];
    bet[cb] = beta[col];
  }

#pragma unroll
  for (int rb = 0; rb < 4; ++rb) {
#pragma unroll
    for (int r = 0; r < 4; ++r) {
      float s = 0.f, ss = 0.f;
#pragma unroll
      for (int cb = 0; cb < 4; ++cb) {
        float v = acc[rb][cb][r] + bia[cb];
        v = fmaxf(v, 0.f);
        acc[rb][cb][r] = v;
        s += v;
        ss += v * v;
      }
#pragma unroll
      for (int m = 1; m < 16; m <<= 1) {
        s += __shfl_xor(s, m);
        ss += __shfl_xor(ss, m);
      }
      if (cl == 0) {
        int row = rb * 16 + gq * 4 + r;
        red[row * 8 + w] = make_float2(s, ss);
      }
    }
  }
  __syncthreads();

#pragma unroll
  for (int rb = 0; rb < 4; ++rb) {
#pragma unroll
    for (int r = 0; r < 4; ++r) {
      int row = rb * 16 + gq * 4 + r;
      float S = 0.f, SS = 0.f;
#pragma unroll
      for (int wv = 0; wv < 8; ++wv) {
        float2 p = red[row * 8 + wv];
        S += p.x;
        SS += p.y;
      }
      float mu = S * (1.f / 512.f);
      float var = SS * (1.f / 512.f) - mu * mu;
      float rstd = rsqrtf(var + EPS);
      int g = blk * 64 + row;
      if (g < N_ROWS) {
        float* orow = out + (size_t)g * 512 + wcol;
#pragma unroll
        for (int cb = 0; cb < 4; ++cb)
          orow[cb * 16 + cl] = (acc[rb][cb][r] - mu) * rstd * gam[cb] + bet[cb];
      }
    }
  }
}

extern "C" void kernel_launch(void* const* d_in, const int* in_sizes, int n_in,
                              void* d_out, int out_size, void* d_ws, size_t ws_size,
                              hipStream_t stream) {
  const float* f1 = (const float*)d_in[0];
  const int* i1 = (const int*)d_in[1];
  const float* f2 = (const float*)d_in[2];
  const int* i2 = (const int*)d_in[3];
  const float* f3 = (const float*)d_in[4];
  const int* i3 = (const int*)d_in[5];
  const float* f4 = (const float*)d_in[6];
  const int* i4 = (const int*)d_in[7];
  const float* W = (const float*)d_in[8];
  const float* b = (const float*)d_in[9];
  const float* gm = (const float*)d_in[10];
  const float* bt = (const float*)d_in[11];
  float* out = (float*)d_out;
  ushort* Wf = (ushort*)d_ws;  // 512 KB fragment-linear bf16 W

  wconv2_kernel<<<128, 256, 0, stream>>>(W, Wf);
  fused2_kernel<<<(N_ROWS + 63) / 64, 512, 0, stream>>>(
      f1, f2, f3, f4, i1, i2, i3, i4, Wf, b, gm, bt, out);
}

// Round 3
// 153.426 us; speedup vs baseline: 1.4129x; 1.0410x over previous
//
#include <hip/hip_runtime.h>
#include <stdint.h>

#define N_ROWS 100000
#define EPS 1e-6f

typedef float f32x4 __attribute__((ext_vector_type(4)));
typedef __bf16 bf16x8 __attribute__((ext_vector_type(8)));

__device__ __forceinline__ ushort f2bf(float f) {
  union { float f; uint32_t u; } v; v.f = f;
  uint32_t u = v.u;
  return (ushort)((u + 0x7FFFu + ((u >> 16) & 1u)) >> 16);
}

// ---- W f32 -> bf16 fragment-linear rearrange ----
// Wf: frag = j16*16 + kt (kt = k/32), lane l holds W[j16*16+(l&15)][kt*32+(l>>4)*8 .. +8]
// offset = (frag*64 + l)*8 ushorts. Wave fragment load = 1KB fully coalesced.
__global__ __launch_bounds__(256) void wconv2_kernel(const float* __restrict__ W,
                                                     ushort* __restrict__ Wf) {
  int t = blockIdx.x * 256 + threadIdx.x;  // 0..32767
  int frag = t >> 6;
  int lane = t & 63;
  int j = (frag >> 4) * 16 + (lane & 15);
  int kb = (frag & 15) * 32 + (lane >> 4) * 8;
  const float* src = W + j * 512 + kb;
  float4 a = *(const float4*)src;
  float4 b = *(const float4*)(src + 4);
  ushort4 lo, hi;
  lo.x = f2bf(a.x); lo.y = f2bf(a.y); lo.z = f2bf(a.z); lo.w = f2bf(a.w);
  hi.x = f2bf(b.x); hi.y = f2bf(b.y); hi.z = f2bf(b.z); hi.w = f2bf(b.w);
  ushort* dst = Wf + (size_t)t * 8;
  *(ushort4*)dst = lo;
  *(ushort4*)(dst + 4) = hi;
}

// ---- fused gather + GEMM + bias + relu + layernorm ----
// 512 threads = 8 waves; tile 64 rows x 512 cols; wave w -> cols [64w, 64w+64).
// K-loop = 4 macro-steps (one feat table each, BK=128):
//   gather whole 512B rows (4x128B coalesced bursts), 1 barrier per macro-step,
//   1-macro-deep prefetch; B fragments direct L2->VGPR (no LDS for B).
__global__ __launch_bounds__(512, 4) void fused3_kernel(
    const float* __restrict__ f1, const float* __restrict__ f2,
    const float* __restrict__ f3, const float* __restrict__ f4,
    const int* __restrict__ i1, const int* __restrict__ i2,
    const int* __restrict__ i3, const int* __restrict__ i4,
    const ushort* __restrict__ Wf, const float* __restrict__ bias,
    const float* __restrict__ gamma, const float* __restrict__ beta,
    float* __restrict__ out) {
  __shared__ ushort Al[2][64 * 128];  // 2 x 16 KB A double-buffer (bf16, swizzled)
  __shared__ float2 red[64 * 8];      // 4 KB LN cross-wave reduce

  const int t = threadIdx.x;
  const int w = t >> 6;
  const int l = t & 63;
  const int cl = l & 15;
  const int gq = l >> 4;
  const int blk = blockIdx.x;

  // A gather: thread covers row (t>>3), floats e8*4 + q*32 .. +4 (q=0..3)
  const int arow = t >> 3;
  const int e8 = t & 7;
  int gi = blk * 64 + arow;
  int gic = gi < N_ROWS ? gi : (N_ROWS - 1);
  const float* ap0 = f1 + (size_t)i1[gic] * 128 + e8 * 4;
  const float* ap1 = f2 + (size_t)i2[gic] * 128 + e8 * 4;
  const float* ap2 = f3 + (size_t)i3[gic] * 128 + e8 * 4;
  const float* ap3 = f4 + (size_t)i4[gic] * 128 + e8 * 4;

  // ds_write offsets (ushort units), chunk-swizzled: chunk' = chunk ^ (row&15)
  // q-th piece: chunk = q*4 | (e8>>1); off = row*128 + chunk'*8 + (e8&1)*4
  int wboff[4];
#pragma unroll
  for (int q = 0; q < 4; ++q)
    wboff[q] = arow * 128 + (((q * 4) | (e8 >> 1)) ^ (arow & 15)) * 8 + (e8 & 1) * 4;

  // B fragment base: wave w covers j16 = w*4+cb; frag(j16,kt) at ((j16*16+kt)*64+l)*8
  const ushort* Bbase = Wf + ((size_t)w * 4 * 16 * 64 + l) * 8;

  f32x4 acc[4][4];
#pragma unroll
  for (int rb = 0; rb < 4; ++rb)
#pragma unroll
    for (int cb = 0; cb < 4; ++cb)
      acc[rb][cb] = (f32x4){0.f, 0.f, 0.f, 0.f};

  // prologue: gather table 0, stage into Al[0]
  {
    float4 pv[4];
#pragma unroll
    for (int q = 0; q < 4; ++q) pv[q] = *(const float4*)(ap0 + q * 32);
#pragma unroll
    for (int q = 0; q < 4; ++q) {
      ushort4 ab;
      ab.x = f2bf(pv[q].x); ab.y = f2bf(pv[q].y);
      ab.z = f2bf(pv[q].z); ab.w = f2bf(pv[q].w);
      *(ushort4*)(Al[0] + wboff[q]) = ab;
    }
  }
  __syncthreads();

#pragma unroll
  for (int T = 0; T < 4; ++T) {
    const ushort* Acur = Al[T & 1];
    // prefetch next table's rows (whole 512B per row, 4x128B bursts)
    float4 nv[4];
    if (T < 3) {
      const float* ap = (T == 0) ? ap1 : (T == 1) ? ap2 : ap3;
#pragma unroll
      for (int q = 0; q < 4; ++q) nv[q] = *(const float4*)(ap + q * 32);
    }
    // 4 MFMA sub-steps over this table's 128 k
#pragma unroll
    for (int kt = 0; kt < 4; ++kt) {
      bf16x8 bfr[4];
#pragma unroll
      for (int cb = 0; cb < 4; ++cb)
        bfr[cb] = *(const bf16x8*)(Bbase + ((size_t)cb * 16 + T * 4 + kt) * 512);
      bf16x8 af[4];
#pragma unroll
      for (int rb = 0; rb < 4; ++rb) {
        const int chunk = ((kt * 4) | gq) ^ cl;  // swizzled 16B chunk
        af[rb] = *(const bf16x8*)(Acur + (rb * 16 + cl) * 128 + chunk * 8);
      }
#pragma unroll
      for (int cb = 0; cb < 4; ++cb)
#pragma unroll
        for (int rb = 0; rb < 4; ++rb)
          acc[rb][cb] = __builtin_amdgcn_mfma_f32_16x16x32_bf16(
              af[rb], bfr[cb], acc[rb][cb], 0, 0, 0);
    }
    // stage prefetched rows into the other buffer
    if (T < 3) {
      ushort* Anx = Al[(T & 1) ^ 1];
#pragma unroll
      for (int q = 0; q < 4; ++q) {
        ushort4 ab;
        ab.x = f2bf(nv[q].x); ab.y = f2bf(nv[q].y);
        ab.z = f2bf(nv[q].z); ab.w = f2bf(nv[q].w);
        *(ushort4*)(Anx + wboff[q]) = ab;
      }
    }
    __syncthreads();
  }

  // ---- epilogue: bias + relu + layernorm(512) ----
  const int wcol = w * 64;
  float bia[4], gam[4], bet[4];
#pragma unroll
  for (int cb = 0; cb < 4; ++cb) {
    int col = wcol + cb * 16 + cl;
    bia[cb] = bias[col];
    gam[cb] = gamma[col];
    bet[cb] = beta[col];
  }

#pragma unroll
  for (int rb = 0; rb < 4; ++rb) {
#pragma unroll
    for (int r = 0; r < 4; ++r) {
      float s = 0.f, ss = 0.f;
#pragma unroll
      for (int cb = 0; cb < 4; ++cb) {
        float v = acc[rb][cb][r] + bia[cb];
        v = fmaxf(v, 0.f);
        acc[rb][cb][r] = v;
        s += v;
        ss += v * v;
      }
#pragma unroll
      for (int m = 1; m < 16; m <<= 1) {
        s += __shfl_xor(s, m);
        ss += __shfl_xor(ss, m);
      }
      if (cl == 0) {
        int row = rb * 16 + gq * 4 + r;
        red[row * 8 + w] = make_float2(s, ss);
      }
    }
  }
  __syncthreads();

#pragma unroll
  for (int rb = 0; rb < 4; ++rb) {
#pragma unroll
    for (int r = 0; r < 4; ++r) {
      int row = rb * 16 + gq * 4 + r;
      float S = 0.f, SS = 0.f;
#pragma unroll
      for (int wv = 0; wv < 8; ++wv) {
        float2 p = red[row * 8 + wv];
        S += p.x;
        SS += p.y;
      }
      float mu = S * (1.f / 512.f);
      float var = SS * (1.f / 512.f) - mu * mu;
      float rstd = rsqrtf(var + EPS);
      int g = blk * 64 + row;
      if (g < N_ROWS) {
        float* orow = out + (size_t)g * 512 + wcol;
#pragma unroll
        for (int cb = 0; cb < 4; ++cb) {
          float v = (acc[rb][cb][r] - mu) * rstd * gam[cb] + bet[cb];
          __builtin_nontemporal_store(v, &orow[cb * 16 + cl]);
        }
      }
    }
  }
}

extern "C" void kernel_launch(void* const* d_in, const int* in_sizes, int n_in,
                              void* d_out, int out_size, void* d_ws, size_t ws_size,
                              hipStream_t stream) {
  const float* f1 = (const float*)d_in[0];
  const int* i1 = (const int*)d_in[1];
  const float* f2 = (const float*)d_in[2];
  const int* i2 = (const int*)d_in[3];
  const float* f3 = (const float*)d_in[4];
  const int* i3 = (const int*)d_in[5];
  const float* f4 = (const float*)d_in[6];
  const int* i4 = (const int*)d_in[7];
  const float* W = (const float*)d_in[8];
  const float* b = (const float*)d_in[9];
  const float* gm = (const float*)d_in[10];
  const float* bt = (const float*)d_in[11];
  float* out = (float*)d_out;
  ushort* Wf = (ushort*)d_ws;  // 512 KB fragment-linear bf16 W

  wconv2_kernel<<<128, 256, 0, stream>>>(W, Wf);
  fused3_kernel<<<(N_ROWS + 63) / 64, 512, 0, stream>>>(
      f1, f2, f3, f4, i1, i2, i3, i4, Wf, b, gm, bt, out);
}